// Round 1
// baseline (88.344 us; speedup 1.0000x reference)
//
#include <hip/hip_runtime.h>

// DCN forward: B=4, H=128, W=128, G=8, C=32, K=8
// inputs      [B,H,W,G,C]   fp32
// deformables [B,H,W,G,K,2] fp32
// weights     [B,H,W,G,K]   fp32
// out         [B,H,W,G,C]   fp32

#define Bc 4
#define Hc 128
#define Wc 128
#define Gc 8
#define Cc 32
#define Kc 8

typedef float float4v __attribute__((ext_vector_type(4)));

__global__ __launch_bounds__(256) void dcn_fwd(
    const float* __restrict__ inp,
    const float* __restrict__ def,
    const float* __restrict__ wts,
    float* __restrict__ out)
{
    const int t  = blockIdx.x * 256 + threadIdx.x;  // total = B*H*W*G*(C/4)
    const int c4 = t & 7;          // which float4 of the 32 channels
    const int pg = t >> 3;         // pixel-group index: ((b*H + h)*W + w)*G + g
    const int g  = pg & 7;
    const int w  = (pg >> 3) & 127;
    const int h  = (pg >> 10) & 127;
    const int b  = pg >> 17;

    const float wf = (float)w;
    const float hf = (float)h;

    const float* defp = def + (size_t)pg * (Kc * 2);
    const float* wtp  = wts + (size_t)pg * Kc;
    // base points at this (b, g, c4) slice; per-corner offset = (y*W + x)*G*C
    const float* base = inp + (size_t)b * (Hc * Wc * Gc * Cc) + g * Cc + c4 * 4;

    float4v acc = {0.f, 0.f, 0.f, 0.f};

#pragma unroll
    for (int k = 0; k < Kc; ++k) {
        const float dx = defp[2 * k];
        const float dy = defp[2 * k + 1];
        const float wk = wtp[k];

        const float x = dx + wf;
        const float y = dy + hf;

        // truncation toward zero, matching .astype(int32)
        const int fx = (int)x;
        const int fy = (int)y;
        const int cx = fx + 1;
        const int cy = fy + 1;

        const float wx1 = x - (float)fx;
        const float wx0 = (float)cx - x;
        const float wy1 = y - (float)fy;
        const float wy0 = (float)cy - y;

        // per-axis bilinear weight * in-bounds mask
        const float ax0 = (fx >= 0 && fx < Wc) ? wx0 : 0.f;
        const float ax1 = (cx >= 0 && cx < Wc) ? wx1 : 0.f;
        const float ay0 = (fy >= 0 && fy < Hc) ? wy0 : 0.f;
        const float ay1 = (cy >= 0 && cy < Hc) ? wy1 : 0.f;

        // clamped gather coordinates
        const int xf = min(max(fx, 0), Wc - 1);
        const int xc = min(max(cx, 0), Wc - 1);
        const int yf = min(max(fy, 0), Hc - 1);
        const int yc = min(max(cy, 0), Hc - 1);

        const float4v v00 = *(const float4v*)(base + ((yf * Wc + xf) << 8));
        const float4v v01 = *(const float4v*)(base + ((yf * Wc + xc) << 8));
        const float4v v10 = *(const float4v*)(base + ((yc * Wc + xf) << 8));
        const float4v v11 = *(const float4v*)(base + ((yc * Wc + xc) << 8));

        const float c00 = wk * (ay0 * ax0);
        const float c01 = wk * (ay0 * ax1);
        const float c10 = wk * (ay1 * ax0);
        const float c11 = wk * (ay1 * ax1);

        acc += c00 * v00;
        acc += c01 * v01;
        acc += c10 * v10;
        acc += c11 * v11;
    }

    *(float4v*)(out + (size_t)pg * Cc + c4 * 4) = acc;
}

extern "C" void kernel_launch(void* const* d_in, const int* in_sizes, int n_in,
                              void* d_out, int out_size, void* d_ws, size_t ws_size,
                              hipStream_t stream) {
    const float* inp = (const float*)d_in[0];
    const float* def = (const float*)d_in[1];
    const float* wts = (const float*)d_in[2];
    float* out = (float*)d_out;

    const int total = Bc * Hc * Wc * Gc * (Cc / 4);  // 4,194,304 threads
    dcn_fwd<<<total / 256, 256, 0, stream>>>(inp, def, wts, out);
}

// Round 2
// 81.004 us; speedup vs baseline: 1.0906x; 1.0906x over previous
//
#include <hip/hip_runtime.h>

// DCN forward: B=4, H=128, W=128, G=8, C=32, K=8
// inputs      [B,H,W,G,C]   fp32
// deformables [B,H,W,G,K,2] fp32
// weights     [B,H,W,G,K]   fp32
// out         [B,H,W,G,C]   fp32
//
// Block = 4x8 spatial tile of ONE (b,g) plane, 8 lanes (c4) per pixel.
// Rationale: offsets ~ N(0,1) => gather footprint of a tile ~= 19 KB, fits
// 32 KB L1 with ~6.6x line reuse (vs ~100 KB working set in the linear map).

#define Bc 4
#define Hc 128
#define Wc 128
#define Gc 8
#define Cc 32
#define Kc 8
#define TH 4
#define TW 8

typedef float float4v __attribute__((ext_vector_type(4)));

__global__ __launch_bounds__(256) void dcn_fwd(
    const float* __restrict__ inp,
    const float* __restrict__ def,
    const float* __restrict__ wts,
    float* __restrict__ out)
{
    const int tid = threadIdx.x;
    const int c4  = tid & 7;       // which float4 of the 32 channels
    const int p   = tid >> 3;      // 0..31 pixel slot in tile
    const int pw  = p & 7;         // 0..7
    const int ph  = p >> 3;        // 0..3

    // grid: w-tile fastest (16), then h-tile (32), then g (8), then b (4)
    const int blk = blockIdx.x;
    const int wt = blk & 15;
    const int ht = (blk >> 4) & 31;
    const int g  = (blk >> 9) & 7;
    const int b  = blk >> 12;

    const int h = ht * TH + ph;
    const int w = wt * TW + pw;
    const int pg = ((b * Hc + h) * Wc + w) * Gc + g;

    const float wf = (float)w;
    const float hf = (float)h;

    const float* defp = def + (size_t)pg * (Kc * 2);
    const float* wtp  = wts + (size_t)pg * Kc;
    // base points at this (b, g, c4) slice; per-corner offset = (y*W + x)*G*C
    const float* base = inp + (size_t)b * (Hc * Wc * Gc * Cc) + g * Cc + c4 * 4;

    float4v acc = {0.f, 0.f, 0.f, 0.f};

#pragma unroll
    for (int k = 0; k < Kc; ++k) {
        const float dx = defp[2 * k];
        const float dy = defp[2 * k + 1];
        const float wk = wtp[k];

        const float x = dx + wf;
        const float y = dy + hf;

        // truncation toward zero, matching .astype(int32)
        const int fx = (int)x;
        const int fy = (int)y;
        const int cx = fx + 1;
        const int cy = fy + 1;

        const float wx1 = x - (float)fx;
        const float wx0 = (float)cx - x;
        const float wy1 = y - (float)fy;
        const float wy0 = (float)cy - y;

        // per-axis bilinear weight * in-bounds mask
        const float ax0 = (fx >= 0 && fx < Wc) ? wx0 : 0.f;
        const float ax1 = (cx >= 0 && cx < Wc) ? wx1 : 0.f;
        const float ay0 = (fy >= 0 && fy < Hc) ? wy0 : 0.f;
        const float ay1 = (cy >= 0 && cy < Hc) ? wy1 : 0.f;

        // clamped gather coordinates
        const int xf = min(max(fx, 0), Wc - 1);
        const int xc = min(max(cx, 0), Wc - 1);
        const int yf = min(max(fy, 0), Hc - 1);
        const int yc = min(max(cy, 0), Hc - 1);

        const float4v v00 = *(const float4v*)(base + ((yf * Wc + xf) << 8));
        const float4v v01 = *(const float4v*)(base + ((yf * Wc + xc) << 8));
        const float4v v10 = *(const float4v*)(base + ((yc * Wc + xf) << 8));
        const float4v v11 = *(const float4v*)(base + ((yc * Wc + xc) << 8));

        const float c00 = wk * (ay0 * ax0);
        const float c01 = wk * (ay0 * ax1);
        const float c10 = wk * (ay1 * ax0);
        const float c11 = wk * (ay1 * ax1);

        acc += c00 * v00;
        acc += c01 * v01;
        acc += c10 * v10;
        acc += c11 * v11;
    }

    *(float4v*)(out + (size_t)pg * Cc + c4 * 4) = acc;
}

extern "C" void kernel_launch(void* const* d_in, const int* in_sizes, int n_in,
                              void* d_out, int out_size, void* d_ws, size_t ws_size,
                              hipStream_t stream) {
    const float* inp = (const float*)d_in[0];
    const float* def = (const float*)d_in[1];
    const float* wts = (const float*)d_in[2];
    float* out = (float*)d_out;

    const int nblocks = Bc * Gc * (Hc / TH) * (Wc / TW);  // 16384
    dcn_fwd<<<nblocks, 256, 0, stream>>>(inp, def, wts, out);
}

// Round 3
// 80.548 us; speedup vs baseline: 1.0968x; 1.0057x over previous
//
#include <hip/hip_runtime.h>
#include <stdint.h>

// DCN forward: B=4, H=128, W=128, G=8, C=32, K=8
// inputs      [B,H,W,G,C]   fp32
// deformables [B,H,W,G,K,2] fp32
// weights     [B,H,W,G,K]   fp32
// out         [B,H,W,G,C]   fp32
//
// Block = 4x8 spatial tile of ONE (b,g) plane, 8 lanes (c4) per pixel.
// R3: phase-split (all addresses+weights precomputed, then pure load+FMA)
// to maximize outstanding gathers per wave; 32-bit voffsets off a
// block-uniform SGPR base.

#define Bc 4
#define Hc 128
#define Wc 128
#define Gc 8
#define Cc 32
#define Kc 8
#define TH 4
#define TW 8

typedef float float4v __attribute__((ext_vector_type(4)));

__global__ __launch_bounds__(256) void dcn_fwd(
    const float* __restrict__ inp,
    const float* __restrict__ def,
    const float* __restrict__ wts,
    float* __restrict__ out)
{
    const int tid = threadIdx.x;
    const int c4  = tid & 7;       // which float4 of the 32 channels
    const int p   = tid >> 3;      // 0..31 pixel slot in tile
    const int pw  = p & 7;
    const int ph  = p >> 3;

    // grid: w-tile fastest (16), then h-tile (32), then g (8), then b (4)
    const int blk = blockIdx.x;
    const int wt = blk & 15;
    const int ht = (blk >> 4) & 31;
    const int g  = (blk >> 9) & 7;
    const int b  = blk >> 12;

    const int h = ht * TH + ph;
    const int w = wt * TW + pw;
    const int pg = ((b * Hc + h) * Wc + w) * Gc + g;

    // vectorized def/wts loads (16 + 8 floats, 16B-aligned)
    const float4v d0 = *(const float4v*)(def + (size_t)pg * 16 + 0);
    const float4v d1 = *(const float4v*)(def + (size_t)pg * 16 + 4);
    const float4v d2 = *(const float4v*)(def + (size_t)pg * 16 + 8);
    const float4v d3 = *(const float4v*)(def + (size_t)pg * 16 + 12);
    const float4v q0 = *(const float4v*)(wts + (size_t)pg * 8 + 0);
    const float4v q1 = *(const float4v*)(wts + (size_t)pg * 8 + 4);

    const float dxs[8] = {d0.x, d0.z, d1.x, d1.z, d2.x, d2.z, d3.x, d3.z};
    const float dys[8] = {d0.y, d0.w, d1.y, d1.w, d2.y, d2.w, d3.y, d3.w};
    const float wks[8] = {q0.x, q0.y, q0.z, q0.w, q1.x, q1.y, q1.z, q1.w};

    const float wf = (float)w;
    const float hf = (float)h;
    const uint32_t c16 = (uint32_t)c4 * 16u;

    // Phase 1: all corner byte-offsets + combined weights (no mem deps left)
    uint32_t off00[8], off01[8], off10[8], off11[8];
    float    cw00[8], cw01[8], cw10[8], cw11[8];

#pragma unroll
    for (int k = 0; k < Kc; ++k) {
        const float x = dxs[k] + wf;
        const float y = dys[k] + hf;

        // truncation toward zero, matching .astype(int32)
        const int fx = (int)x;
        const int fy = (int)y;
        const int cx = fx + 1;
        const int cy = fy + 1;

        const float wx1 = x - (float)fx;
        const float wx0 = (float)cx - x;
        const float wy1 = y - (float)fy;
        const float wy0 = (float)cy - y;

        // in-bounds mask via unsigned compare (negatives wrap huge)
        const float ax0 = ((uint32_t)fx < (uint32_t)Wc) ? wx0 : 0.f;
        const float ax1 = ((uint32_t)cx < (uint32_t)Wc) ? wx1 : 0.f;
        const float ay0 = ((uint32_t)fy < (uint32_t)Hc) ? wy0 : 0.f;
        const float ay1 = ((uint32_t)cy < (uint32_t)Hc) ? wy1 : 0.f;

        // clamped gather coordinates (addresses always valid)
        const int xf = min(max(fx, 0), Wc - 1);
        const int xc = min(max(cx, 0), Wc - 1);
        const int yf = min(max(fy, 0), Hc - 1);
        const int yc = min(max(cy, 0), Hc - 1);

        // byte offsets: row stride = W*G*C*4 = 1<<17, cell stride = G*C*4 = 1<<10
        const uint32_t xa = ((uint32_t)xf << 10) + c16;
        const uint32_t xb = ((uint32_t)xc << 10) + c16;
        const uint32_t ya = (uint32_t)yf << 17;
        const uint32_t yb = (uint32_t)yc << 17;
        off00[k] = ya + xa;
        off01[k] = ya + xb;
        off10[k] = yb + xa;
        off11[k] = yb + xb;

        const float wk = wks[k];
        cw00[k] = wk * (ay0 * ax0);
        cw01[k] = wk * (ay0 * ax1);
        cw10[k] = wk * (ay1 * ax0);
        cw11[k] = wk * (ay1 * ax1);
    }

    // block-uniform base (b,g fixed per block) -> SGPR base + 32-bit voffset
    const char* base = (const char*)inp
        + (size_t)b * (Hc * Wc * Gc * Cc * 4)
        + (size_t)(g * Cc * 4);

    // Phase 2: pure gather + FMA, two accumulators to shorten dep chain
    float4v acc0 = {0.f, 0.f, 0.f, 0.f};
    float4v acc1 = {0.f, 0.f, 0.f, 0.f};

#pragma unroll
    for (int k = 0; k < Kc; ++k) {
        const float4v v00 = *(const float4v*)(base + off00[k]);
        const float4v v01 = *(const float4v*)(base + off01[k]);
        const float4v v10 = *(const float4v*)(base + off10[k]);
        const float4v v11 = *(const float4v*)(base + off11[k]);
        acc0 += cw00[k] * v00;
        acc1 += cw01[k] * v01;
        acc0 += cw10[k] * v10;
        acc1 += cw11[k] * v11;
    }

    const float4v acc = acc0 + acc1;
    *(float4v*)((char*)out + (size_t)pg * (Cc * 4) + c16) = acc;
}

extern "C" void kernel_launch(void* const* d_in, const int* in_sizes, int n_in,
                              void* d_out, int out_size, void* d_ws, size_t ws_size,
                              hipStream_t stream) {
    const float* inp = (const float*)d_in[0];
    const float* def = (const float*)d_in[1];
    const float* wts = (const float*)d_in[2];
    float* out = (float*)d_out;

    const int nblocks = Bc * Gc * (Hc / TH) * (Wc / TW);  // 16384
    dcn_fwd<<<nblocks, 256, 0, stream>>>(inp, def, wts, out);
}